// Round 2
// baseline (230.473 us; speedup 1.0000x reference)
//
#include <hip/hip_runtime.h>
#include <math.h>

// LightConv1d: B=8, C=1024, T=4096, H=16, K=7, causal pad L=6.
// out[b,c,t] = sum_k softmax(w)[c%16,k] * x[b,c,t-6+k] + bias[c%16]
//
// One block per row (b*C+c): h = blockIdx.x & 15 is scalar-uniform, so
// weight/bias loads are s_loads and softmax is computed in scalar regs
// (redundantly per thread — ~30 VALU ops, negligible vs 42 us HBM floor).
// Row staged in LDS with coalesced float4 loads; windows read from LDS
// (consecutive lanes -> consecutive quads, <=2-way bank alias = free);
// stores coalesced float4. Single kernel launch.
#define TT 4096
#define KK 7
#define HH 16

__global__ __launch_bounds__(256) void lightconv_kernel(
    const float* __restrict__ x, const float* __restrict__ w,
    const float* __restrict__ bias, float* __restrict__ out) {
    const int row = blockIdx.x;          // 8192 rows
    const int h   = row & (HH - 1);      // uniform (SGPR)

    // softmax(w[h,:]) in (scalar) registers
    float wk[KK];
    #pragma unroll
    for (int k = 0; k < KK; ++k) wk[k] = w[h * KK + k];
    float m = wk[0];
    #pragma unroll
    for (int k = 1; k < KK; ++k) m = fmaxf(m, wk[k]);
    float s = 0.f;
    #pragma unroll
    for (int k = 0; k < KK; ++k) { wk[k] = __expf(wk[k] - m); s += wk[k]; }
    const float inv = 1.f / s;
    #pragma unroll
    for (int k = 0; k < KK; ++k) wk[k] *= inv;
    const float bb = bias[h];

    // LDS: quad 0,1 = zero halo (x quads -2,-1); quads 2..1025 = row quads 0..1023
    __shared__ float4 sv[2 + TT / 4];
    const float4* xr = (const float4*)(x + (size_t)row * TT);
    const int tid = threadIdx.x;
    if (tid < 2) sv[tid] = make_float4(0.f, 0.f, 0.f, 0.f);
    #pragma unroll
    for (int n = 0; n < 4; ++n) sv[2 + n * 256 + tid] = xr[n * 256 + tid];
    __syncthreads();

    float4* outr = (float4*)(out + (size_t)row * TT);
    #pragma unroll
    for (int n = 0; n < 4; ++n) {
        const int q = n * 256 + tid;     // output quad within row
        // window: x floats [4q-8 .. 4q+3] = sv quads q, q+1, q+2
        float4 a = sv[q];
        float4 b = sv[q + 1];
        float4 c = sv[q + 2];
        float f[12] = {a.x, a.y, a.z, a.w, b.x, b.y, b.z, b.w,
                       c.x, c.y, c.z, c.w};
        float4 o;
        float* op = &o.x;
        #pragma unroll
        for (int j = 0; j < 4; ++j) {
            // out[4q+j] = bb + sum_k wk[k] * x[4q+j-6+k] = bb + sum_k wk[k]*f[j+k+2]
            float acc = bb;
            #pragma unroll
            for (int k = 0; k < KK; ++k) acc = fmaf(wk[k], f[j + k + 2], acc);
            op[j] = acc;
        }
        outr[q] = o;
    }
}

extern "C" void kernel_launch(void* const* d_in, const int* in_sizes, int n_in,
                              void* d_out, int out_size, void* d_ws, size_t ws_size,
                              hipStream_t stream) {
    const float* x    = (const float*)d_in[0];
    const float* w    = (const float*)d_in[1];
    const float* bias = (const float*)d_in[2];
    float* out = (float*)d_out;

    const int rows = out_size / TT;      // 8192 = B*C
    lightconv_kernel<<<rows, 256, 0, stream>>>(x, w, bias, out);
}

// Round 3
// 229.947 us; speedup vs baseline: 1.0023x; 1.0023x over previous
//
#include <hip/hip_runtime.h>
#include <math.h>

// LightConv1d: B=8, C=1024, T=4096, H=16, K=7, causal pad L=6.
// out[b,c,t] = sum_k softmax(w)[c%16,k] * x[b,c,t-6+k] + bias[c%16]
//
// One block per row: h = blockIdx.x & 15 is SGPR-uniform -> weight/bias are
// s_loads, softmax computed in scalar regs (~30 ops, negligible).
// No LDS, no barrier (R2 showed LDS round-trip + sync costs more than the
// L1-absorbed overlap): each thread computes 4 output quads from 3
// overlapping float4 window loads each; HBM traffic stays exactly 1x read +
// 1x write, overlap served by L1/L2.
#define TT 4096
#define KK 7
#define HH 16

__global__ __launch_bounds__(256) void lightconv_kernel(
    const float* __restrict__ x, const float* __restrict__ w,
    const float* __restrict__ bias, float* __restrict__ out) {
    const int row = blockIdx.x;          // 8192 rows = B*C
    const int h   = row & (HH - 1);      // uniform (SGPR)
    const int tid = threadIdx.x;

    // softmax(w[h,:]) — uniform h -> scalar loads + scalar math
    float wk[KK];
    #pragma unroll
    for (int k = 0; k < KK; ++k) wk[k] = w[h * KK + k];
    float m = wk[0];
    #pragma unroll
    for (int k = 1; k < KK; ++k) m = fmaxf(m, wk[k]);
    float s = 0.f;
    #pragma unroll
    for (int k = 0; k < KK; ++k) { wk[k] = __expf(wk[k] - m); s += wk[k]; }
    const float inv = 1.f / s;
    #pragma unroll
    for (int k = 0; k < KK; ++k) wk[k] *= inv;
    const float bb = bias[h];

    const float4* xr   = (const float4*)(x + (size_t)row * TT);
    float4*       outr = (float4*)(out + (size_t)row * TT);
    const float4  z    = make_float4(0.f, 0.f, 0.f, 0.f);

    #pragma unroll
    for (int n = 0; n < 4; ++n) {
        const int q = n * 256 + tid;     // output quad within row (0..1023)
        // window floats [4q-8 .. 4q+3] = quads q-2, q-1, q
        float4 c = xr[q];
        float4 a = (q >= 2) ? xr[q - 2] : z;
        float4 b = (q >= 1) ? xr[q - 1] : z;
        float f[12] = {a.x, a.y, a.z, a.w, b.x, b.y, b.z, b.w,
                       c.x, c.y, c.z, c.w};
        float4 o;
        float* op = &o.x;
        #pragma unroll
        for (int j = 0; j < 4; ++j) {
            // out[4q+j] = bb + sum_k wk[k]*f[j+k+2]
            float acc = bb;
            #pragma unroll
            for (int k = 0; k < KK; ++k) acc = fmaf(wk[k], f[j + k + 2], acc);
            op[j] = acc;
        }
        outr[q] = o;
    }
}

extern "C" void kernel_launch(void* const* d_in, const int* in_sizes, int n_in,
                              void* d_out, int out_size, void* d_ws, size_t ws_size,
                              hipStream_t stream) {
    const float* x    = (const float*)d_in[0];
    const float* w    = (const float*)d_in[1];
    const float* bias = (const float*)d_in[2];
    float* out = (float*)d_out;

    const int rows = out_size / TT;      // 8192 = B*C
    lightconv_kernel<<<rows, 256, 0, stream>>>(x, w, bias, out);
}